// Round 1
// baseline (5197.017 us; speedup 1.0000x reference)
//
#include <hip/hip_runtime.h>
#include <hip/hip_cooperative_groups.h>

namespace cg = cooperative_groups;

static constexpr int B_ = 8;
static constexpr int N_ = 16384;
static constexpr int D_ = 256;
static constexpr int L_ = 64;

// ---------------------------------------------------------------------------
// Stage 1: MaxMin (farthest-point) landmark selection.
// Cooperative kernel: 512 WGs (64 per batch) x 256 threads; 1 point/thread.
// min_d lives in a register. One grid.sync per step; per-WG argmax candidates
// are parity double-buffered so a single sync per step suffices.
// ---------------------------------------------------------------------------
__global__ void __launch_bounds__(256)
fps_kernel(const float* __restrict__ emb, const float* __restrict__ csp,
           float* __restrict__ xn, int* __restrict__ lm_idx,
           float* __restrict__ pval, int* __restrict__ pidx,
           unsigned char* __restrict__ adj)
{
    cg::grid_group grid = cg::this_grid();
    const int wg  = blockIdx.x;       // 0..511
    const int b   = wg >> 6;          // batch
    const int wib = wg & 63;          // wg-in-batch
    const int tid = threadIdx.x;
    const int n   = (wib << 8) + tid; // my point (0..16383)
    const float c = fabsf(csp[0]);

    // zero the adjacency byte matrix for stage 2 (ws is poisoned 0xAA)
    const int gid = wg * 256 + tid;
    if (gid < B_ * L_ * L_) adj[gid] = 0;

    const float4* pt = (const float4*)(emb + (size_t)(b * N_ + n) * D_);

    // squared norm of my point (kept in a register, also stored for reuse)
    float s0 = 0.f, s1 = 0.f, s2 = 0.f, s3 = 0.f;
    #pragma unroll 8
    for (int k = 0; k < D_ / 4; ++k) {
        float4 v = pt[k];
        s0 = fmaf(v.x, v.x, s0); s1 = fmaf(v.y, v.y, s1);
        s2 = fmaf(v.z, v.z, s2); s3 = fmaf(v.w, v.w, s3);
    }
    const float my_xn = (s0 + s1) + (s2 + s3);
    xn[b * N_ + n] = my_xn;

    __shared__ __align__(16) float lmbuf[D_];
    __shared__ float rval[256];
    __shared__ int   ridx[256];
    __shared__ int   s_next;

    float min_d = __builtin_inff();
    int lmIdx = 0;
    if (wib == 0 && tid == 0) lm_idx[b * L_] = 0;   // seed landmark = index 0

    grid.sync();   // xn visible grid-wide

    int parity = 0;
    for (int s = 1; s < L_; ++s) {
        // stage current landmark vector into LDS (1 float per thread)
        lmbuf[tid] = emb[(size_t)(b * N_ + lmIdx) * D_ + tid];
        const float lmn = xn[b * N_ + lmIdx];
        __syncthreads();

        const float4* lmv4 = (const float4*)lmbuf;
        float d0 = 0.f, d1 = 0.f, d2 = 0.f, d3 = 0.f;
        #pragma unroll 8
        for (int k = 0; k < D_ / 4; ++k) {
            float4 v = pt[k];
            float4 w = lmv4[k];
            d0 = fmaf(v.x, w.x, d0); d1 = fmaf(v.y, w.y, d1);
            d2 = fmaf(v.z, w.z, d2); d3 = fmaf(v.w, w.w, d3);
        }
        const float dot  = (d0 + d1) + (d2 + d3);
        const float diff = fmaxf(my_xn + lmn - 2.f * dot, 1e-10f);
        const float fac  = fmaxf(1.f + c * my_xn + c * lmn, 1e-6f);
        const float d    = sqrtf(diff) * sqrtf(fac);
        min_d = fminf(min_d, d);

        // block argmax of (min_d, n), ties -> lower index (matches jnp.argmax)
        rval[tid] = min_d; ridx[tid] = n;
        __syncthreads();
        #pragma unroll
        for (int st = 128; st >= 1; st >>= 1) {
            if (tid < st) {
                float ov = rval[tid + st]; int oi = ridx[tid + st];
                float mv = rval[tid];      int mi = ridx[tid];
                if (ov > mv || (ov == mv && oi < mi)) { rval[tid] = ov; ridx[tid] = oi; }
            }
            __syncthreads();
        }
        if (tid == 0) {
            pval[(parity * B_ + b) * 64 + wib] = rval[0];
            pidx[(parity * B_ + b) * 64 + wib] = ridx[0];
        }
        grid.sync();

        // every WG redundantly reduces its batch's 64 candidates (wave 0)
        if (tid < 64) {
            float v = pval[(parity * B_ + b) * 64 + tid];
            int   i = pidx[(parity * B_ + b) * 64 + tid];
            #pragma unroll
            for (int off = 32; off >= 1; off >>= 1) {
                float ov = __shfl_down(v, off);
                int   oi = __shfl_down(i, off);
                if (ov > v || (ov == v && oi < i)) { v = ov; i = oi; }
            }
            if (tid == 0) s_next = i;
        }
        __syncthreads();
        lmIdx = s_next;
        if (wib == 0 && tid == 0) lm_idx[b * L_ + s] = lmIdx;
        parity ^= 1;
    }
}

// ---------------------------------------------------------------------------
// Stage 2: witness edges. Each thread owns 2 points; landmarks staged in LDS
// in 2 chunks of 32 (32 KB tile). Track top-2 nearest landmarks with top_k
// tie semantics (strict <, ascending landmark index scan). The edge-weight
// VALUES are never consumed by the reference (only isfinite), so we just set
// a byte in the adjacency matrix.
// ---------------------------------------------------------------------------
__global__ void __launch_bounds__(256)
witness_kernel(const float* __restrict__ emb, const float* __restrict__ csp,
               const float* __restrict__ xn, const int* __restrict__ lm_idx,
               unsigned char* __restrict__ adj)
{
    const int wg  = blockIdx.x;     // B_*32 = 256 WGs
    const int b   = wg >> 5;
    const int blk = wg & 31;        // 512-point block
    const int tid = threadIdx.x;
    const float c = fabsf(csp[0]);

    __shared__ __align__(16) float lmv[32 * 256];
    __shared__ float lmn_s[64];
    __shared__ int   lidx_s[64];

    if (tid < 64) {
        int li = lm_idx[b * 64 + tid];
        lidx_s[tid] = li;
        lmn_s[tid]  = xn[b * N_ + li];
    }
    __syncthreads();

    const int p0 = blk * 512 + tid;   // my two points: p0, p0+256
    const float mxn0 = xn[b * N_ + p0];
    const float mxn1 = xn[b * N_ + p0 + 256];
    const float4* ptA = (const float4*)(emb + (size_t)(b * N_ + p0) * D_);
    const float4* ptB = (const float4*)(emb + (size_t)(b * N_ + p0 + 256) * D_);

    float b1v0 = __builtin_inff(), b2v0 = __builtin_inff();
    float b1v1 = __builtin_inff(), b2v1 = __builtin_inff();
    int b1i0 = 0, b2i0 = 0, b1i1 = 0, b2i1 = 0;

    for (int ch = 0; ch < 2; ++ch) {
        __syncthreads();
        // stage 32 landmark rows into LDS (coalesced: 256 floats/row)
        #pragma unroll
        for (int r = 0; r < 32; ++r) {
            lmv[r * 256 + tid] = emb[(size_t)(b * N_ + lidx_s[ch * 32 + r]) * D_ + tid];
        }
        __syncthreads();

        float acc0[32], acc1[32];
        #pragma unroll
        for (int j = 0; j < 32; ++j) { acc0[j] = 0.f; acc1[j] = 0.f; }

        #pragma unroll 2
        for (int k = 0; k < 64; ++k) {
            float4 pA = ptA[k];
            float4 pB = ptB[k];
            #pragma unroll
            for (int j = 0; j < 32; ++j) {
                float4 w = *(const float4*)(&lmv[j * 256 + 4 * k]);  // uniform -> broadcast
                acc0[j] = fmaf(pA.x, w.x, fmaf(pA.y, w.y, fmaf(pA.z, w.z, fmaf(pA.w, w.w, acc0[j]))));
                acc1[j] = fmaf(pB.x, w.x, fmaf(pB.y, w.y, fmaf(pB.z, w.z, fmaf(pB.w, w.w, acc1[j]))));
            }
        }

        #pragma unroll
        for (int j = 0; j < 32; ++j) {
            const int lm = ch * 32 + j;
            const float ln = lmn_s[lm];
            {
                float diff = fmaxf(mxn0 + ln - 2.f * acc0[j], 1e-10f);
                float fac  = fmaxf(1.f + c * mxn0 + c * ln, 1e-6f);
                float d = sqrtf(diff) * sqrtf(fac);
                if (d < b1v0)      { b2v0 = b1v0; b2i0 = b1i0; b1v0 = d; b1i0 = lm; }
                else if (d < b2v0) { b2v0 = d; b2i0 = lm; }
            }
            {
                float diff = fmaxf(mxn1 + ln - 2.f * acc1[j], 1e-10f);
                float fac  = fmaxf(1.f + c * mxn1 + c * ln, 1e-6f);
                float d = sqrtf(diff) * sqrtf(fac);
                if (d < b1v1)      { b2v1 = b1v1; b2i1 = b1i1; b1v1 = d; b1i1 = lm; }
                else if (d < b2v1) { b2v1 = d; b2i1 = lm; }
            }
        }
    }

    {
        int lo = min(b1i0, b2i0), hi = max(b1i0, b2i0);
        adj[(b * 64 + lo) * 64 + hi] = 1;   // racing writes of identical value: benign
    }
    {
        int lo = min(b1i1, b2i1), hi = max(b1i1, b2i1);
        adj[(b * 64 + lo) * 64 + hi] = 1;
    }
}

// ---------------------------------------------------------------------------
// Stage 3: symmetrize, min-label component propagation (64 iters, synchronous
// updates like the reference fori_loop), edge count, betas.
// ---------------------------------------------------------------------------
__global__ void __launch_bounds__(64)
finalize_kernel(const unsigned char* __restrict__ adj, float* __restrict__ out)
{
    const int b = blockIdx.x;
    const int t = threadIdx.x;   // 64 threads = 64 landmarks
    __shared__ int labels[64];

    unsigned long long m = 0ull;
    for (int j = 0; j < 64; ++j) {
        if (adj[(b * 64 + t) * 64 + j] | adj[(b * 64 + j) * 64 + t])
            m |= (1ull << j);
    }
    labels[t] = t;
    __syncthreads();

    for (int it = 0; it < 64; ++it) {
        int mn = labels[t];
        unsigned long long mm = m;
        while (mm) {
            int j = __ffsll(mm) - 1;
            int lj = labels[j];
            mn = mn < lj ? mn : lj;
            mm &= mm - 1;
        }
        __syncthreads();       // all reads of old labels complete
        labels[t] = mn;
        __syncthreads();
    }

    unsigned long long hi_mask = (t < 63) ? (~0ull << (t + 1)) : 0ull;
    int myedges = __popcll(m & hi_mask);
    int mycomp  = (labels[t] == t) ? 1 : 0;

    for (int off = 32; off >= 1; off >>= 1) {
        myedges += __shfl_down(myedges, off);
        mycomp  += __shfl_down(mycomp, off);
    }
    if (t == 0) {
        float beta0 = (float)mycomp;
        float beta1 = (float)(myedges - (64 - mycomp));
        out[b]      = beta0;
        out[8 + b]  = beta1;
        out[16 + b] = beta0 / 64.f;
        out[24 + b] = (beta1 > 3.f) ? 1.f : 0.f;
    }
}

// ---------------------------------------------------------------------------
extern "C" void kernel_launch(void* const* d_in, const int* in_sizes, int n_in,
                              void* d_out, int out_size, void* d_ws, size_t ws_size,
                              hipStream_t stream)
{
    const float* emb = (const float*)d_in[0];
    const float* cs  = (const float*)d_in[1];
    float* out = (float*)d_out;

    char* ws = (char*)d_ws;
    float*         xn   = (float*)(ws);                         // 8*16384*4 = 524288 B
    int*           lmi  = (int*)  (ws + 524288);                // 2048 B (pad to 4096)
    float*         pval = (float*)(ws + 524288 + 4096);         // 2*8*64*4 = 4096 B
    int*           pidx = (int*)  (ws + 524288 + 8192);         // 4096 B
    unsigned char* adj  = (unsigned char*)(ws + 524288 + 12288);// 8*64*64 = 32768 B

    void* args[] = { (void*)&emb, (void*)&cs, (void*)&xn, (void*)&lmi,
                     (void*)&pval, (void*)&pidx, (void*)&adj };
    hipLaunchCooperativeKernel((void*)fps_kernel, dim3(512), dim3(256),
                               args, 0, stream);

    hipLaunchKernelGGL(witness_kernel, dim3(B_ * 32), dim3(256), 0, stream,
                       emb, cs, xn, lmi, adj);
    hipLaunchKernelGGL(finalize_kernel, dim3(B_), dim3(64), 0, stream,
                       adj, out);
}